// Round 8
// baseline (68.341 us; speedup 1.0000x reference)
//
#include <hip/hip_runtime.h>

typedef short short8 __attribute__((ext_vector_type(8)));
typedef float f32x4 __attribute__((ext_vector_type(4)));

#define DK 64
#define BM 64     // users per block
#define BN 128    // movies per tile
#define TMOV 8    // movie tiles looped per block

// f32 -> bf16 round-to-nearest-even
__device__ __forceinline__ short f2bf(float x) {
    unsigned u = __builtin_bit_cast(unsigned, x);
    unsigned r = (u + 0x7fffu + ((u >> 16) & 1u)) >> 16;
    return (short)r;
}

__device__ __forceinline__ void gl_lds16(const void* g, void* l) {
    __builtin_amdgcn_global_load_lds(
        (const __attribute__((address_space(1))) unsigned int*)g,
        (__attribute__((address_space(3))) unsigned int*)l, 16, 0, 0);
}

// ---------------- Phase 1: bf16 convert (value + square), pre-swizzled ------
// ws (shorts): [wsU: NUP*64][wsU2: NUP*64][wsM: NMP*64][wsM2: NMP*64]
// Rows stored with 16B chunk p holding source chunk p^(row&7): a LINEAR
// global_load_lds copy then yields the XOR-swizzled LDS layout (rule #21).
__global__ __launch_bounds__(256)
void fm_convert(const float* __restrict__ U, const float* __restrict__ M,
                short* __restrict__ ws, int NU, int NM, int NUP, int NMP) {
    int id = blockIdx.x * blockDim.x + threadIdx.x;
    int total = (NUP + NMP) * 8;
    if (id >= total) return;
    int rowg = id >> 3;
    int p = id & 7;                 // 16B chunk within the 64-wide row
    const float* src; short *dv, *dq; int row, nvalid;
    if (rowg < NUP) {
        row = rowg; src = U; dv = ws; dq = ws + (size_t)NUP * DK; nvalid = NU;
    } else {
        row = rowg - NUP; src = M;
        dv = ws + (size_t)2 * NUP * DK; dq = dv + (size_t)NMP * DK; nvalid = NM;
    }
    short8 v8 = {0,0,0,0,0,0,0,0}, q8 = {0,0,0,0,0,0,0,0};
    if (row < nvalid) {
        const int cp = p ^ (row & 7);
        const float* s = src + (size_t)row * DK + cp * 8;
        float4 a = *(const float4*)(s);
        float4 b = *(const float4*)(s + 4);
        v8 = (short8){ f2bf(a.x), f2bf(a.y), f2bf(a.z), f2bf(a.w),
                       f2bf(b.x), f2bf(b.y), f2bf(b.z), f2bf(b.w) };
        q8 = (short8){ f2bf(a.x*a.x), f2bf(a.y*a.y), f2bf(a.z*a.z), f2bf(a.w*a.w),
                       f2bf(b.x*b.x), f2bf(b.y*b.y), f2bf(b.z*b.z), f2bf(b.w*b.w) };
    }
    *(short8*)(dv + (size_t)row * DK + p * 8) = v8;
    *(short8*)(dq + (size_t)row * DK + p * 8) = q8;
}

// ---------------- Phase 2: fused double-GEMM, movie-loop per block ----------
// R5 structure (A staged once, TMOV=8 movie tiles looped, B staged once
// globally -> staging 300MB -> 38MB) with the SINGLE delta: NORMAL stores
// instead of nontemporal (NT bypassed L2 write-merging of the 64B row
// segments -> ~2x write amplification; every NT round regressed >=68us).
__global__ __launch_bounds__(256, 3)
void fm_gemm(const short* __restrict__ ws, float* __restrict__ out,
             int NM, int NMP, int NUP, int NMT) {
    __shared__ short sA [BM * DK];   // 8 KB user values
    __shared__ short sA2[BM * DK];   // 8 KB user squares
    __shared__ short sB [BN * DK];   // 16 KB movie values
    __shared__ short sB2[BN * DK];   // 16 KB movie squares -> 48 KB

    const int t = threadIdx.x;
    const int lane = t & 63;
    const int w = t >> 6;            // wave 0..3 -> movie quadrant within tile
    const int lr = lane & 15;
    const int lk = lane >> 4;

    const short* gU  = ws;
    const short* gU2 = ws + (size_t)NUP * DK;
    const short* gM  = ws + (size_t)2 * NUP * DK;
    const short* gM2 = gM + (size_t)NMP * DK;

    const int ub = blockIdx.x * BM;
    const int g0 = blockIdx.y * TMOV;
    const int gend = (g0 + TMOV < NMT) ? (g0 + TMOV) : NMT;
    const int lo = lane * 8;         // lane's 16B within a 1KB chunk (shorts)

    // ---- stage A once: 8 KB per array = 8 x 1KB chunks / 4 waves ----
    {
        const short* srcA  = gU  + (size_t)ub * DK;
        const short* srcA2 = gU2 + (size_t)ub * DK;
#pragma unroll
        for (int i = 0; i < 2; ++i) {
            const int ch = w * 2 + i;
            gl_lds16(srcA  + ch * 512 + lo, &sA [ch * 512]);
            gl_lds16(srcA2 + ch * 512 + lo, &sA2[ch * 512]);
        }
    }

#pragma unroll 1
    for (int mt = g0; mt < gend; ++mt) {
        if (mt != g0) __syncthreads();   // B reads of prev iter done

        // ---- stage B tile mt: 16 KB per array = 16 chunks / 4 waves ----
        {
            const short* srcB  = gM  + (size_t)mt * BN * DK;
            const short* srcB2 = gM2 + (size_t)mt * BN * DK;
#pragma unroll
            for (int i = 0; i < 4; ++i) {
                const int ch = w * 4 + i;
                gl_lds16(srcB  + ch * 512 + lo, &sB [ch * 512]);
                gl_lds16(srcB2 + ch * 512 + lo, &sB2[ch * 512]);
            }
        }
        __syncthreads();                 // stage complete (A too on iter 0)

        // ---- fragments (swizzled reads) ----
        short8 av[4][2], aq[4][2];       // users: [m][ks]
#pragma unroll
        for (int m = 0; m < 4; ++m)
#pragma unroll
            for (int ks = 0; ks < 2; ++ks) {
                const int row = m * 16 + lr;
                const int c = ks * 4 + lk;
                const int idx = row * DK + ((c ^ (row & 7)) << 3);
                av[m][ks] = *(const short8*)&sA [idx];
                aq[m][ks] = *(const short8*)&sA2[idx];
            }
        short8 bv[2][2], bq[2][2];       // movies: [n][ks], wave quadrant
#pragma unroll
        for (int n = 0; n < 2; ++n)
#pragma unroll
            for (int ks = 0; ks < 2; ++ks) {
                const int row = w * 32 + n * 16 + lr;
                const int c = ks * 4 + lk;
                const int idx = row * DK + ((c ^ (row & 7)) << 3);
                bv[n][ks] = *(const short8*)&sB [idx];
                bq[n][ks] = *(const short8*)&sB2[idx];
            }

        f32x4 s[4][2], q[4][2];
#pragma unroll
        for (int m = 0; m < 4; ++m)
#pragma unroll
            for (int n = 0; n < 2; ++n) {
                s[m][n] = (f32x4){0.f, 0.f, 0.f, 0.f};
                q[m][n] = (f32x4){0.f, 0.f, 0.f, 0.f};
            }

#pragma unroll
        for (int m = 0; m < 4; ++m)
#pragma unroll
            for (int n = 0; n < 2; ++n)
#pragma unroll
                for (int ks = 0; ks < 2; ++ks) {
                    // transposed: D[movie][user]; lane -> user lr, movies lk*4+reg
                    s[m][n] = __builtin_amdgcn_mfma_f32_16x16x32_bf16(bv[n][ks], av[m][ks], s[m][n], 0, 0, 0);
                    q[m][n] = __builtin_amdgcn_mfma_f32_16x16x32_bf16(bq[n][ks], aq[m][ks], q[m][n], 0, 0, 0);
                }

        // ---- epilogue: user row ub+m*16+lr, movie cols mt*128+w*32+n*16+lk*4 ----
        const int nbW = mt * BN + w * 32;
#pragma unroll
        for (int m = 0; m < 4; ++m) {
            float* rowp = out + (size_t)(ub + m * 16 + lr) * NM;
#pragma unroll
            for (int n = 0; n < 2; ++n) {
                const int col = nbW + n * 16 + lk * 4;
                if (col < NM) {
                    f32x4 sv = s[m][n], qv = q[m][n];
                    f32x4 r;
#pragma unroll
                    for (int i = 0; i < 4; ++i)
                        r[i] = 0.5f * (sv[i] * sv[i] - qv[i]);
                    *(f32x4*)(rowp + col) = r;   // NORMAL store (the one delta)
                }
            }
        }
    }
}

// ---------------- Fallback (round-1 kernel) ---------------------------------
__global__ __launch_bounds__(256, 2)
void fm_fallback(const float* __restrict__ U, const float* __restrict__ M,
                 float* __restrict__ out, int NU, int NM) {
    __shared__ short sA [128 * DK];
    __shared__ short sA2[128 * DK];
    __shared__ short sB [128 * DK];
    __shared__ short sB2[128 * DK];

    const int t = threadIdx.x;
    const int lane = t & 63;
    const int w = t >> 6;
    const int wr = w >> 1;
    const int wc = w & 1;
    const int lr = lane & 15;
    const int lk = lane >> 4;

    const int mbase = blockIdx.x * 128;
    const int nbase = blockIdx.y * 128;

    const int r0 = t >> 4;
    const int c4 = t & 15;
    const int chunk = c4 >> 1;
    const int sub = c4 & 1;

    typedef short short4v __attribute__((ext_vector_type(4)));
#pragma unroll
    for (int i = 0; i < 8; ++i) {
        const int r = r0 + i * 16;
        const int sidx = r * DK + ((chunk ^ (r & 7)) << 3) + (sub << 2);
        {
            float4 v = make_float4(0.f, 0.f, 0.f, 0.f);
            const int gr = mbase + r;
            if (gr < NU) v = *(const float4*)(U + (size_t)gr * DK + c4 * 4);
            short4v b  = { f2bf(v.x), f2bf(v.y), f2bf(v.z), f2bf(v.w) };
            short4v b2 = { f2bf(v.x*v.x), f2bf(v.y*v.y), f2bf(v.z*v.z), f2bf(v.w*v.w) };
            *(short4v*)&sA[sidx] = b; *(short4v*)&sA2[sidx] = b2;
        }
        {
            float4 v = make_float4(0.f, 0.f, 0.f, 0.f);
            const int gr = nbase + r;
            if (gr < NM) v = *(const float4*)(M + (size_t)gr * DK + c4 * 4);
            short4v b  = { f2bf(v.x), f2bf(v.y), f2bf(v.z), f2bf(v.w) };
            short4v b2 = { f2bf(v.x*v.x), f2bf(v.y*v.y), f2bf(v.z*v.z), f2bf(v.w*v.w) };
            *(short4v*)&sB[sidx] = b; *(short4v*)&sB2[sidx] = b2;
        }
    }
    __syncthreads();

    f32x4 accS[4][4], accQ[4][4];
#pragma unroll
    for (int m = 0; m < 4; ++m)
#pragma unroll
        for (int n = 0; n < 4; ++n) {
            accS[m][n] = (f32x4){0.f,0.f,0.f,0.f};
            accQ[m][n] = (f32x4){0.f,0.f,0.f,0.f};
        }
#pragma unroll
    for (int ks = 0; ks < 2; ++ks) {
        short8 af[4], a2f[4], bfr[4], b2f[4];
        const int c = ks * 4 + lk;
#pragma unroll
        for (int m = 0; m < 4; ++m) {
            const int row = wr * 64 + m * 16 + lr;
            const int idx = row * DK + ((c ^ (row & 7)) << 3);
            af[m] = *(const short8*)&sA[idx]; a2f[m] = *(const short8*)&sA2[idx];
        }
#pragma unroll
        for (int n = 0; n < 4; ++n) {
            const int row = wc * 64 + n * 16 + lr;
            const int idx = row * DK + ((c ^ (row & 7)) << 3);
            bfr[n] = *(const short8*)&sB[idx]; b2f[n] = *(const short8*)&sB2[idx];
        }
#pragma unroll
        for (int m = 0; m < 4; ++m)
#pragma unroll
            for (int n = 0; n < 4; ++n) {
                accS[m][n] = __builtin_amdgcn_mfma_f32_16x16x32_bf16(af[m],  bfr[n], accS[m][n], 0, 0, 0);
                accQ[m][n] = __builtin_amdgcn_mfma_f32_16x16x32_bf16(a2f[m], b2f[n], accQ[m][n], 0, 0, 0);
            }
    }
#pragma unroll
    for (int m = 0; m < 4; ++m) {
        const int grow0 = mbase + wr * 64 + m * 16 + lk * 4;
#pragma unroll
        for (int n = 0; n < 4; ++n) {
            const int gcol = nbase + wc * 64 + n * 16 + lr;
            if (gcol < NM) {
                f32x4 s = accS[m][n]; f32x4 q = accQ[m][n];
#pragma unroll
                for (int r = 0; r < 4; ++r) {
                    const int grow = grow0 + r;
                    if (grow < NU)
                        out[(size_t)grow * NM + gcol] = 0.5f * (s[r]*s[r] - q[r]);
                }
            }
        }
    }
}

extern "C" void kernel_launch(void* const* d_in, const int* in_sizes, int n_in,
                              void* d_out, int out_size, void* d_ws, size_t ws_size,
                              hipStream_t stream) {
    const float* U = (const float*)d_in[0];
    const float* M = (const float*)d_in[1];
    float* out = (float*)d_out;
    const int NU = in_sizes[0] / DK;   // 1024
    const int NM = in_sizes[1] / DK;   // 50000
    const int NUP = NU;
    const int NMP = ((NM + BN - 1) / BN) * BN;
    const int NMT = NMP / BN;          // movie tiles (391)
    const size_t need = (size_t)(NUP + NMP) * DK * 2 * sizeof(short);

    if ((NU % BM == 0) && (NM % 4 == 0) && ws_size >= need) {
        short* ws = (short*)d_ws;
        const int tasks = (NUP + NMP) * 8;
        fm_convert<<<(tasks + 255) / 256, 256, 0, stream>>>(U, M, ws, NU, NM, NUP, NMP);
        dim3 grid(NU / BM, (NMT + TMOV - 1) / TMOV);
        fm_gemm<<<grid, dim3(256), 0, stream>>>(ws, out, NM, NMP, NUP, NMT);
    } else {
        dim3 grid((NU + 127) / 128, (NM + 127) / 128);
        fm_fallback<<<grid, dim3(256), 0, stream>>>(U, M, out, NU, NM);
    }
}

// Round 9
// 50.972 us; speedup vs baseline: 1.3408x; 1.3408x over previous
//
#include <hip/hip_runtime.h>

typedef short short8 __attribute__((ext_vector_type(8)));
typedef float f32x4 __attribute__((ext_vector_type(4)));

#define DK 64
#define BM 64     // users per block
#define BN 128    // movies per block

// f32 -> bf16 round-to-nearest-even
__device__ __forceinline__ short f2bf(float x) {
    unsigned u = __builtin_bit_cast(unsigned, x);
    unsigned r = (u + 0x7fffu + ((u >> 16) & 1u)) >> 16;
    return (short)r;
}

// elementwise bf16 square of a bf16x8 fragment (exact f32 product,
// round-half-up repack — error ~2^-9 rel, negligible vs threshold)
__device__ __forceinline__ short8 sq8(short8 v) {
    short8 r;
#pragma unroll
    for (int i = 0; i < 8; ++i) {
        unsigned u = ((unsigned)(unsigned short)v[i]) << 16;
        float f = __builtin_bit_cast(float, u);
        unsigned p = __builtin_bit_cast(unsigned, f * f);
        r[i] = (short)((p + 0x8000u) >> 16);
    }
    return r;
}

__device__ __forceinline__ void gl_lds16(const void* g, void* l) {
    __builtin_amdgcn_global_load_lds(
        (const __attribute__((address_space(1))) unsigned int*)g,
        (__attribute__((address_space(3))) unsigned int*)l, 16, 0, 0);
}

// ---------------- Phase 1: bf16 convert (VALUES ONLY), pre-swizzled ---------
// ws (shorts): [wsU: NUP*64][wsM: NMP*64]  (~6.5 MB — fits per-XCD L2)
// Rows stored with 16B chunk p holding source chunk p^(row&7): a LINEAR
// global_load_lds copy then yields the XOR-swizzled LDS layout (rule #21).
// Squares are derived in-register in the GEMM (sq8), not staged.
__global__ __launch_bounds__(256)
void fm_convert(const float* __restrict__ U, const float* __restrict__ M,
                short* __restrict__ ws, int NU, int NM, int NUP, int NMP) {
    int id = blockIdx.x * blockDim.x + threadIdx.x;
    int total = (NUP + NMP) * 8;
    if (id >= total) return;
    int rowg = id >> 3;
    int p = id & 7;                 // 16B chunk within the 64-wide row
    const float* src; short* dv; int row, nvalid;
    if (rowg < NUP) {
        row = rowg; src = U; dv = ws; nvalid = NU;
    } else {
        row = rowg - NUP; src = M;
        dv = ws + (size_t)NUP * DK; nvalid = NM;
    }
    short8 v8 = {0,0,0,0,0,0,0,0};
    if (row < nvalid) {
        const int cp = p ^ (row & 7);
        const float* s = src + (size_t)row * DK + cp * 8;
        float4 a = *(const float4*)(s);
        float4 b = *(const float4*)(s + 4);
        v8 = (short8){ f2bf(a.x), f2bf(a.y), f2bf(a.z), f2bf(a.w),
                       f2bf(b.x), f2bf(b.y), f2bf(b.z), f2bf(b.w) };
    }
    *(short8*)(dv + (size_t)row * DK + p * 8) = v8;
}

// ---------------- Phase 2: single-shot fused double-GEMM, 24 KB LDS ---------
// R7's proven single-shot skeleton (2D grid x-fastest, one stage, ONE
// barrier, no in-block loops) with: values-only staging (24 KB LDS),
// in-register squares (sq8), per-m fragment/acc liveness (~80 VGPR) ->
// __launch_bounds__(256,5): 5 blocks/CU (was 3). Transposed MFMA ->
// 8 f32x4 normal stores/thread (L2 merges 64B row segments).
__global__ __launch_bounds__(256, 5)
void fm_gemm(const short* __restrict__ ws, float* __restrict__ out,
             int NM, int NMP, int NUP) {
    __shared__ short sA[BM * DK];    // 8 KB user values
    __shared__ short sB[BN * DK];    // 16 KB movie values -> 24 KB total

    const int t = threadIdx.x;
    const int lane = t & 63;
    const int w = t >> 6;            // wave 0..3 -> movie quadrant (32 cols)
    const int lr = lane & 15;
    const int lk = lane >> 4;

    const int ub  = blockIdx.x * BM;   // user base
    const int nb0 = blockIdx.y * BN;   // movie base

    const short* gU = ws;
    const short* gM = ws + (size_t)NUP * DK;

    // ---- stage: A 8 KB + B 16 KB via global_load_lds (linear dest) ----
    {
        const short* srcA = gU + (size_t)ub * DK;
        const short* srcB = gM + (size_t)nb0 * DK;
        const int lo = lane * 8;                  // lane's 16B in a 1KB chunk
#pragma unroll
        for (int j = 0; j < 2; ++j) {             // A: 8 chunks / 4 waves
            const int ch = w * 2 + j;
            gl_lds16(srcA + ch * 512 + lo, &sA[ch * 512]);
        }
#pragma unroll
        for (int j = 0; j < 4; ++j) {             // B: 16 chunks / 4 waves
            const int ch = w * 4 + j;
            gl_lds16(srcB + ch * 512 + lo, &sB[ch * 512]);
        }
    }
    __syncthreads();

    // ---- B fragments (swizzled reads) + derived squares ----
    short8 bv[2][2], bq[2][2];       // movies: [n][ks], wave quadrant
#pragma unroll
    for (int n = 0; n < 2; ++n)
#pragma unroll
        for (int ks = 0; ks < 2; ++ks) {
            const int row = w * 32 + n * 16 + lr;
            const int c = ks * 4 + lk;
            const int idx = row * DK + ((c ^ (row & 7)) << 3);
            bv[n][ks] = *(const short8*)&sB[idx];
            bq[n][ks] = sq8(bv[n][ks]);
        }

    const int nbW = nb0 + w * 32;

    // ---- per-m: load A frags, derive squares, 8 MFMAs, 2 stores ----
#pragma unroll
    for (int m = 0; m < 4; ++m) {
        short8 av0, av1, aq0, aq1;
        {
            const int row = m * 16 + lr;
            const int i0 = row * DK + (((0 * 4 + lk) ^ (row & 7)) << 3);
            const int i1 = row * DK + (((1 * 4 + lk) ^ (row & 7)) << 3);
            av0 = *(const short8*)&sA[i0];
            av1 = *(const short8*)&sA[i1];
            aq0 = sq8(av0);
            aq1 = sq8(av1);
        }

        f32x4 s[2], q[2];
#pragma unroll
        for (int n = 0; n < 2; ++n) {
            s[n] = (f32x4){0.f, 0.f, 0.f, 0.f};
            q[n] = (f32x4){0.f, 0.f, 0.f, 0.f};
        }
#pragma unroll
        for (int n = 0; n < 2; ++n) {
            // transposed: D[movie][user] -> lane holds user col lr,
            // 4 consecutive movie cols lk*4+reg (layout proven R5-R8)
            s[n] = __builtin_amdgcn_mfma_f32_16x16x32_bf16(bv[n][0], av0, s[n], 0, 0, 0);
            s[n] = __builtin_amdgcn_mfma_f32_16x16x32_bf16(bv[n][1], av1, s[n], 0, 0, 0);
            q[n] = __builtin_amdgcn_mfma_f32_16x16x32_bf16(bq[n][0], aq0, q[n], 0, 0, 0);
            q[n] = __builtin_amdgcn_mfma_f32_16x16x32_bf16(bq[n][1], aq1, q[n], 0, 0, 0);
        }

        float* rowp = out + (size_t)(ub + m * 16 + lr) * NM;
#pragma unroll
        for (int n = 0; n < 2; ++n) {
            const int col = nbW + n * 16 + lk * 4;
            if (col < NM) {
                f32x4 sv = s[n], qv = q[n];
                f32x4 rr;
#pragma unroll
                for (int j = 0; j < 4; ++j)
                    rr[j] = 0.5f * (sv[j] * sv[j] - qv[j]);
                *(f32x4*)(rowp + col) = rr;
            }
        }
    }
}

// ---------------- Fallback (round-1 kernel, self-contained) -----------------
__global__ __launch_bounds__(256, 2)
void fm_fallback(const float* __restrict__ U, const float* __restrict__ M,
                 float* __restrict__ out, int NU, int NM) {
    __shared__ short sA [128 * DK];
    __shared__ short sA2[128 * DK];
    __shared__ short sB [128 * DK];
    __shared__ short sB2[128 * DK];

    const int t = threadIdx.x;
    const int lane = t & 63;
    const int w = t >> 6;
    const int wr = w >> 1;
    const int wc = w & 1;
    const int lr = lane & 15;
    const int lk = lane >> 4;

    const int mbase = blockIdx.x * 128;
    const int nbase = blockIdx.y * 128;

    const int r0 = t >> 4;
    const int c4 = t & 15;
    const int chunk = c4 >> 1;
    const int sub = c4 & 1;

    typedef short short4v __attribute__((ext_vector_type(4)));
#pragma unroll
    for (int i = 0; i < 8; ++i) {
        const int r = r0 + i * 16;
        const int sidx = r * DK + ((chunk ^ (r & 7)) << 3) + (sub << 2);
        {
            float4 v = make_float4(0.f, 0.f, 0.f, 0.f);
            const int gr = mbase + r;
            if (gr < NU) v = *(const float4*)(U + (size_t)gr * DK + c4 * 4);
            short4v b  = { f2bf(v.x), f2bf(v.y), f2bf(v.z), f2bf(v.w) };
            short4v b2 = { f2bf(v.x*v.x), f2bf(v.y*v.y), f2bf(v.z*v.z), f2bf(v.w*v.w) };
            *(short4v*)&sA[sidx] = b; *(short4v*)&sA2[sidx] = b2;
        }
        {
            float4 v = make_float4(0.f, 0.f, 0.f, 0.f);
            const int gr = nbase + r;
            if (gr < NM) v = *(const float4*)(M + (size_t)gr * DK + c4 * 4);
            short4v b  = { f2bf(v.x), f2bf(v.y), f2bf(v.z), f2bf(v.w) };
            short4v b2 = { f2bf(v.x*v.x), f2bf(v.y*v.y), f2bf(v.z*v.z), f2bf(v.w*v.w) };
            *(short4v*)&sB[sidx] = b; *(short4v*)&sB2[sidx] = b2;
        }
    }
    __syncthreads();

    f32x4 accS[4][4], accQ[4][4];
#pragma unroll
    for (int m = 0; m < 4; ++m)
#pragma unroll
        for (int n = 0; n < 4; ++n) {
            accS[m][n] = (f32x4){0.f,0.f,0.f,0.f};
            accQ[m][n] = (f32x4){0.f,0.f,0.f,0.f};
        }
#pragma unroll
    for (int ks = 0; ks < 2; ++ks) {
        short8 af[4], a2f[4], bfr[4], b2f[4];
        const int c = ks * 4 + lk;
#pragma unroll
        for (int m = 0; m < 4; ++m) {
            const int row = wr * 64 + m * 16 + lr;
            const int idx = row * DK + ((c ^ (row & 7)) << 3);
            af[m] = *(const short8*)&sA[idx]; a2f[m] = *(const short8*)&sA2[idx];
        }
#pragma unroll
        for (int n = 0; n < 4; ++n) {
            const int row = wc * 64 + n * 16 + lr;
            const int idx = row * DK + ((c ^ (row & 7)) << 3);
            bfr[n] = *(const short8*)&sB[idx]; b2f[n] = *(const short8*)&sB2[idx];
        }
#pragma unroll
        for (int m = 0; m < 4; ++m)
#pragma unroll
            for (int n = 0; n < 4; ++n) {
                accS[m][n] = __builtin_amdgcn_mfma_f32_16x16x32_bf16(af[m],  bfr[n], accS[m][n], 0, 0, 0);
                accQ[m][n] = __builtin_amdgcn_mfma_f32_16x16x32_bf16(a2f[m], b2f[n], accQ[m][n], 0, 0, 0);
            }
    }
#pragma unroll
    for (int m = 0; m < 4; ++m) {
        const int grow0 = mbase + wr * 64 + m * 16 + lk * 4;
#pragma unroll
        for (int n = 0; n < 4; ++n) {
            const int gcol = nbase + wc * 64 + n * 16 + lr;
            if (gcol < NM) {
                f32x4 s = accS[m][n]; f32x4 q = accQ[m][n];
#pragma unroll
                for (int r = 0; r < 4; ++r) {
                    const int grow = grow0 + r;
                    if (grow < NU)
                        out[(size_t)grow * NM + gcol] = 0.5f * (s[r]*s[r] - q[r]);
                }
            }
        }
    }
}

extern "C" void kernel_launch(void* const* d_in, const int* in_sizes, int n_in,
                              void* d_out, int out_size, void* d_ws, size_t ws_size,
                              hipStream_t stream) {
    const float* U = (const float*)d_in[0];
    const float* M = (const float*)d_in[1];
    float* out = (float*)d_out;
    const int NU = in_sizes[0] / DK;   // 1024
    const int NM = in_sizes[1] / DK;   // 50000
    const int NUP = NU;
    const int NMP = ((NM + BN - 1) / BN) * BN;
    const size_t need = (size_t)(NUP + NMP) * DK * sizeof(short);

    if ((NU % BM == 0) && (NM % 4 == 0) && ws_size >= need) {
        short* ws = (short*)d_ws;
        const int tasks = (NUP + NMP) * 8;
        fm_convert<<<(tasks + 255) / 256, 256, 0, stream>>>(U, M, ws, NU, NM, NUP, NMP);
        dim3 grid(NU / BM, NMP / BN);
        fm_gemm<<<grid, dim3(256), 0, stream>>>(ws, out, NM, NMP, NUP);
    } else {
        dim3 grid((NU + 127) / 128, (NM + 127) / 128);
        fm_fallback<<<grid, dim3(256), 0, stream>>>(U, M, out, NU, NM);
    }
}

// Round 10
// 50.742 us; speedup vs baseline: 1.3468x; 1.0045x over previous
//
#include <hip/hip_runtime.h>

typedef short short8 __attribute__((ext_vector_type(8)));
typedef float f32x4 __attribute__((ext_vector_type(4)));

#define DK 64
#define BM 64     // users per block
#define BN 128    // movies per block

// f32 -> bf16 round-to-nearest-even
__device__ __forceinline__ short f2bf(float x) {
    unsigned u = __builtin_bit_cast(unsigned, x);
    unsigned r = (u + 0x7fffu + ((u >> 16) & 1u)) >> 16;
    return (short)r;
}

// elementwise bf16 square of a bf16x8 fragment (exact f32 product,
// round-half-up repack — error ~2^-9 rel, negligible vs threshold)
__device__ __forceinline__ short8 sq8(short8 v) {
    short8 r;
#pragma unroll
    for (int i = 0; i < 8; ++i) {
        unsigned u = ((unsigned)(unsigned short)v[i]) << 16;
        float f = __builtin_bit_cast(float, u);
        unsigned p = __builtin_bit_cast(unsigned, f * f);
        r[i] = (short)((p + 0x8000u) >> 16);
    }
    return r;
}

__device__ __forceinline__ void gl_lds16(const void* g, void* l) {
    __builtin_amdgcn_global_load_lds(
        (const __attribute__((address_space(1))) unsigned int*)g,
        (__attribute__((address_space(3))) unsigned int*)l, 16, 0, 0);
}

// ---------------- Phase 1: bf16 convert (VALUES ONLY), pre-swizzled ---------
// ws (shorts): [wsU: NUP*64][wsM: NMP*64]  (~6.5 MB — LLC/L2 resident)
// Rows stored with 16B chunk p holding source chunk p^(row&7): a LINEAR
// global_load_lds copy then yields the XOR-swizzled LDS layout (rule #21).
__global__ __launch_bounds__(256)
void fm_convert(const float* __restrict__ U, const float* __restrict__ M,
                short* __restrict__ ws, int NU, int NM, int NUP, int NMP) {
    int id = blockIdx.x * blockDim.x + threadIdx.x;
    int total = (NUP + NMP) * 8;
    if (id >= total) return;
    int rowg = id >> 3;
    int p = id & 7;                 // 16B chunk within the 64-wide row
    const float* src; short* dv; int row, nvalid;
    if (rowg < NUP) {
        row = rowg; src = U; dv = ws; nvalid = NU;
    } else {
        row = rowg - NUP; src = M;
        dv = ws + (size_t)NUP * DK; nvalid = NM;
    }
    short8 v8 = {0,0,0,0,0,0,0,0};
    if (row < nvalid) {
        const int cp = p ^ (row & 7);
        const float* s = src + (size_t)row * DK + cp * 8;
        float4 a = *(const float4*)(s);
        float4 b = *(const float4*)(s + 4);
        v8 = (short8){ f2bf(a.x), f2bf(a.y), f2bf(a.z), f2bf(a.w),
                       f2bf(b.x), f2bf(b.y), f2bf(b.z), f2bf(b.w) };
    }
    *(short8*)(dv + (size_t)row * DK + p * 8) = v8;
}

// ---------------- Phase 2: single-shot fused double-GEMM, 24 KB LDS ---------
// R9 skeleton (single-shot, one barrier, values-only staging, per-m
// epilogue). Delta R10: bq fragments NOT held in registers — recomputed
// per-m from bv via sq8 (−16 VGPR) -> __launch_bounds__(256,6): target
// 6 blocks/CU (24 KB x 6 = 144 KB LDS, needs <=85 VGPR).
__global__ __launch_bounds__(256, 6)
void fm_gemm(const short* __restrict__ ws, float* __restrict__ out,
             int NM, int NMP, int NUP) {
    __shared__ short sA[BM * DK];    // 8 KB user values
    __shared__ short sB[BN * DK];    // 16 KB movie values -> 24 KB total

    const int t = threadIdx.x;
    const int lane = t & 63;
    const int w = t >> 6;            // wave 0..3 -> movie quadrant (32 cols)
    const int lr = lane & 15;
    const int lk = lane >> 4;

    const int ub  = blockIdx.x * BM;   // user base
    const int nb0 = blockIdx.y * BN;   // movie base

    const short* gU = ws;
    const short* gM = ws + (size_t)NUP * DK;

    // ---- stage: A 8 KB + B 16 KB via global_load_lds (linear dest) ----
    {
        const short* srcA = gU + (size_t)ub * DK;
        const short* srcB = gM + (size_t)nb0 * DK;
        const int lo = lane * 8;                  // lane's 16B in a 1KB chunk
#pragma unroll
        for (int j = 0; j < 2; ++j) {             // A: 8 chunks / 4 waves
            const int ch = w * 2 + j;
            gl_lds16(srcA + ch * 512 + lo, &sA[ch * 512]);
        }
#pragma unroll
        for (int j = 0; j < 4; ++j) {             // B: 16 chunks / 4 waves
            const int ch = w * 4 + j;
            gl_lds16(srcB + ch * 512 + lo, &sB[ch * 512]);
        }
    }
    __syncthreads();

    // ---- B value fragments only (squares recomputed per-m) ----
    short8 bv[2][2];                 // movies: [n][ks], wave quadrant
#pragma unroll
    for (int n = 0; n < 2; ++n)
#pragma unroll
        for (int ks = 0; ks < 2; ++ks) {
            const int row = w * 32 + n * 16 + lr;
            const int c = ks * 4 + lk;
            const int idx = row * DK + ((c ^ (row & 7)) << 3);
            bv[n][ks] = *(const short8*)&sB[idx];
        }

    const int nbW = nb0 + w * 32;

    // ---- per-m: load A frags, derive squares, 8 MFMAs, 2 stores ----
#pragma unroll
    for (int m = 0; m < 4; ++m) {
        short8 av0, av1, aq0, aq1;
        {
            const int row = m * 16 + lr;
            const int i0 = row * DK + (((0 * 4 + lk) ^ (row & 7)) << 3);
            const int i1 = row * DK + (((1 * 4 + lk) ^ (row & 7)) << 3);
            av0 = *(const short8*)&sA[i0];
            av1 = *(const short8*)&sA[i1];
            aq0 = sq8(av0);
            aq1 = sq8(av1);
        }

        f32x4 s[2], q[2];
#pragma unroll
        for (int n = 0; n < 2; ++n) {
            s[n] = (f32x4){0.f, 0.f, 0.f, 0.f};
            q[n] = (f32x4){0.f, 0.f, 0.f, 0.f};
        }
#pragma unroll
        for (int n = 0; n < 2; ++n) {
            // transposed: D[movie][user] -> lane holds user col lr,
            // 4 consecutive movie cols lk*4+reg (layout proven R5-R9)
            const short8 bq0 = sq8(bv[n][0]);
            const short8 bq1 = sq8(bv[n][1]);
            s[n] = __builtin_amdgcn_mfma_f32_16x16x32_bf16(bv[n][0], av0, s[n], 0, 0, 0);
            s[n] = __builtin_amdgcn_mfma_f32_16x16x32_bf16(bv[n][1], av1, s[n], 0, 0, 0);
            q[n] = __builtin_amdgcn_mfma_f32_16x16x32_bf16(bq0, aq0, q[n], 0, 0, 0);
            q[n] = __builtin_amdgcn_mfma_f32_16x16x32_bf16(bq1, aq1, q[n], 0, 0, 0);
        }

        float* rowp = out + (size_t)(ub + m * 16 + lr) * NM;
#pragma unroll
        for (int n = 0; n < 2; ++n) {
            const int col = nbW + n * 16 + lk * 4;
            if (col < NM) {
                f32x4 sv = s[n], qv = q[n];
                f32x4 rr;
#pragma unroll
                for (int j = 0; j < 4; ++j)
                    rr[j] = 0.5f * (sv[j] * sv[j] - qv[j]);
                *(f32x4*)(rowp + col) = rr;
            }
        }
    }
}

// ---------------- Fallback (round-1 kernel, self-contained) -----------------
__global__ __launch_bounds__(256, 2)
void fm_fallback(const float* __restrict__ U, const float* __restrict__ M,
                 float* __restrict__ out, int NU, int NM) {
    __shared__ short sA [128 * DK];
    __shared__ short sA2[128 * DK];
    __shared__ short sB [128 * DK];
    __shared__ short sB2[128 * DK];

    const int t = threadIdx.x;
    const int lane = t & 63;
    const int w = t >> 6;
    const int wr = w >> 1;
    const int wc = w & 1;
    const int lr = lane & 15;
    const int lk = lane >> 4;

    const int mbase = blockIdx.x * 128;
    const int nbase = blockIdx.y * 128;

    const int r0 = t >> 4;
    const int c4 = t & 15;
    const int chunk = c4 >> 1;
    const int sub = c4 & 1;

    typedef short short4v __attribute__((ext_vector_type(4)));
#pragma unroll
    for (int i = 0; i < 8; ++i) {
        const int r = r0 + i * 16;
        const int sidx = r * DK + ((chunk ^ (r & 7)) << 3) + (sub << 2);
        {
            float4 v = make_float4(0.f, 0.f, 0.f, 0.f);
            const int gr = mbase + r;
            if (gr < NU) v = *(const float4*)(U + (size_t)gr * DK + c4 * 4);
            short4v b  = { f2bf(v.x), f2bf(v.y), f2bf(v.z), f2bf(v.w) };
            short4v b2 = { f2bf(v.x*v.x), f2bf(v.y*v.y), f2bf(v.z*v.z), f2bf(v.w*v.w) };
            *(short4v*)&sA[sidx] = b; *(short4v*)&sA2[sidx] = b2;
        }
        {
            float4 v = make_float4(0.f, 0.f, 0.f, 0.f);
            const int gr = nbase + r;
            if (gr < NM) v = *(const float4*)(M + (size_t)gr * DK + c4 * 4);
            short4v b  = { f2bf(v.x), f2bf(v.y), f2bf(v.z), f2bf(v.w) };
            short4v b2 = { f2bf(v.x*v.x), f2bf(v.y*v.y), f2bf(v.z*v.z), f2bf(v.w*v.w) };
            *(short4v*)&sB[sidx] = b; *(short4v*)&sB2[sidx] = b2;
        }
    }
    __syncthreads();

    f32x4 accS[4][4], accQ[4][4];
#pragma unroll
    for (int m = 0; m < 4; ++m)
#pragma unroll
        for (int n = 0; n < 4; ++n) {
            accS[m][n] = (f32x4){0.f,0.f,0.f,0.f};
            accQ[m][n] = (f32x4){0.f,0.f,0.f,0.f};
        }
#pragma unroll
    for (int ks = 0; ks < 2; ++ks) {
        short8 af[4], a2f[4], bfr[4], b2f[4];
        const int c = ks * 4 + lk;
#pragma unroll
        for (int m = 0; m < 4; ++m) {
            const int row = wr * 64 + m * 16 + lr;
            const int idx = row * DK + ((c ^ (row & 7)) << 3);
            af[m] = *(const short8*)&sA[idx]; a2f[m] = *(const short8*)&sA2[idx];
        }
#pragma unroll
        for (int n = 0; n < 4; ++n) {
            const int row = wc * 64 + n * 16 + lr;
            const int idx = row * DK + ((c ^ (row & 7)) << 3);
            bfr[n] = *(const short8*)&sB[idx]; b2f[n] = *(const short8*)&sB2[idx];
        }
#pragma unroll
        for (int m = 0; m < 4; ++m)
#pragma unroll
            for (int n = 0; n < 4; ++n) {
                accS[m][n] = __builtin_amdgcn_mfma_f32_16x16x32_bf16(af[m],  bfr[n], accS[m][n], 0, 0, 0);
                accQ[m][n] = __builtin_amdgcn_mfma_f32_16x16x32_bf16(a2f[m], b2f[n], accQ[m][n], 0, 0, 0);
            }
    }
#pragma unroll
    for (int m = 0; m < 4; ++m) {
        const int grow0 = mbase + wr * 64 + m * 16 + lk * 4;
#pragma unroll
        for (int n = 0; n < 4; ++n) {
            const int gcol = nbase + wc * 64 + n * 16 + lr;
            if (gcol < NM) {
                f32x4 s = accS[m][n]; f32x4 q = accQ[m][n];
#pragma unroll
                for (int r = 0; r < 4; ++r) {
                    const int grow = grow0 + r;
                    if (grow < NU)
                        out[(size_t)grow * NM + gcol] = 0.5f * (s[r]*s[r] - q[r]);
                }
            }
        }
    }
}

extern "C" void kernel_launch(void* const* d_in, const int* in_sizes, int n_in,
                              void* d_out, int out_size, void* d_ws, size_t ws_size,
                              hipStream_t stream) {
    const float* U = (const float*)d_in[0];
    const float* M = (const float*)d_in[1];
    float* out = (float*)d_out;
    const int NU = in_sizes[0] / DK;   // 1024
    const int NM = in_sizes[1] / DK;   // 50000
    const int NUP = NU;
    const int NMP = ((NM + BN - 1) / BN) * BN;
    const size_t need = (size_t)(NUP + NMP) * DK * sizeof(short);

    if ((NU % BM == 0) && (NM % 4 == 0) && ws_size >= need) {
        short* ws = (short*)d_ws;
        const int tasks = (NUP + NMP) * 8;
        fm_convert<<<(tasks + 255) / 256, 256, 0, stream>>>(U, M, ws, NU, NM, NUP, NMP);
        dim3 grid(NU / BM, NMP / BN);
        fm_gemm<<<grid, dim3(256), 0, stream>>>(ws, out, NM, NMP, NUP);
    } else {
        dim3 grid((NU + 127) / 128, (NM + 127) / 128);
        fm_fallback<<<grid, dim3(256), 0, stream>>>(U, M, out, NU, NM);
    }
}